// Round 1
// baseline (678.702 us; speedup 1.0000x reference)
//
#include <hip/hip_runtime.h>
#include <hip/hip_bf16.h>
#include <stdint.h>

// ---------- types ----------
typedef __attribute__((ext_vector_type(8))) __bf16 bf16x8;
typedef __attribute__((ext_vector_type(8))) short short8v;
typedef __attribute__((ext_vector_type(4))) short short4v;
typedef __attribute__((ext_vector_type(4))) float f32x4;

__device__ __forceinline__ float bf2f(short u) {
  return __builtin_bit_cast(float, (uint32_t)((uint32_t)(uint16_t)u << 16));
}
__device__ __forceinline__ short f2bf(float f) {
  uint32_t x = __builtin_bit_cast(uint32_t, f);
  x += 0x7FFFu + ((x >> 16) & 1u);
  return (short)(x >> 16);
}
__device__ __forceinline__ f32x4 mfma16(short8v a, short8v b, f32x4 c) {
  return __builtin_amdgcn_mfma_f32_16x16x32_bf16(
      __builtin_bit_cast(bf16x8, a), __builtin_bit_cast(bf16x8, b), c, 0, 0, 0);
}

// ---------- prepack a fp32 [Ks x Ns] row-major weight into MFMA B-fragment order ----------
// dst layout: [nt][kt][lane][8 bf16]; B[k = kt*32 + (lane>>4)*8 + j][n = nt*16 + (lane&15)]
__global__ void prepack_b(const float* __restrict__ src, short* __restrict__ dst,
                          int Ks, int Ns, int KT, int NT) {
  int idx = blockIdx.x * 256 + threadIdx.x;
  int total = NT * KT * 64;
  if (idx >= total) return;
  int lane = idx & 63;
  int tile = idx >> 6;
  int kt = tile % KT, nt = tile / KT;
  int n = nt * 16 + (lane & 15);
  int kbase = kt * 32 + ((lane >> 4) * 8);
  short8v o;
#pragma unroll
  for (int j = 0; j < 8; ++j) {
    int k = kbase + j;
    o[j] = f2bf((k < Ks && n < Ns) ? src[k * Ns + n] : 0.f);
  }
  *(short8v*)&dst[idx * 8] = o;
}

// ---------- qb[b,c] = qst[b] @ Wg1[200:211] + bg1 ----------
__global__ void qb_kernel(const float* __restrict__ qst, const float* __restrict__ Wg1,
                          const float* __restrict__ bg1, float* __restrict__ qb) {
  int b = blockIdx.x, c = threadIdx.x;
  float acc = bg1[c];
#pragma unroll
  for (int k = 0; k < 11; ++k) acc += qst[b * 11 + k] * Wg1[(200 + k) * 256 + c];
  qb[b * 256 + c] = acc;
}

// ---------- encoder: tabs[64 rows x 10] -> x -> u,v (bf16, [obj][256]) ----------
__launch_bounds__(256, 2)
__global__ void enc_kernel(const float* __restrict__ tabs,
    const float* __restrict__ bi1, const float* __restrict__ bi2, const float* __restrict__ bi3,
    const short* __restrict__ Wi1p, const short* __restrict__ Wi2p, const short* __restrict__ Wi3p,
    const short* __restrict__ Wap, const short* __restrict__ Wbp,
    short* __restrict__ u_g, short* __restrict__ v_g) {
  __shared__ __align__(16) short sIn[64 * 40];   // K padded 10->32 (+8 pad)
  __shared__ __align__(16) short sH1[64 * 264];  // 256 (+8)
  __shared__ __align__(16) short sH2[64 * 136];  // 128 (+8)
  __shared__ __align__(16) short sX [64 * 136];  // 128 (100 real, 100..127 = 0)
  const int tid = threadIdx.x;
  const int lane = tid & 63, w = tid >> 6, quad = lane >> 4, ll = lane & 15;
  const int obj0 = blockIdx.x * 64;

  for (int idx = tid; idx < 64 * 40; idx += 256) {
    int r = idx / 40, k = idx - r * 40;
    float v = (k < 10) ? tabs[(obj0 + r) * 10 + k] : 0.f;
    sIn[idx] = f2bf(v);
  }
  __syncthreads();

  // L1: relu(in @ Wi1 + bi1)  K=32(pad), N=256
  {
    f32x4 acc[4][4] = {};
    short8v a[4];
#pragma unroll
    for (int mt = 0; mt < 4; ++mt)
      a[mt] = *(const short8v*)&sIn[(mt * 16 + ll) * 40 + quad * 8];
#pragma unroll
    for (int ni = 0; ni < 4; ++ni) {
      short8v b = *(const short8v*)&Wi1p[((w * 4 + ni) * 64 + lane) * 8];
#pragma unroll
      for (int mt = 0; mt < 4; ++mt) acc[mt][ni] = mfma16(a[mt], b, acc[mt][ni]);
    }
#pragma unroll
    for (int ni = 0; ni < 4; ++ni) {
      int col = (w * 4 + ni) * 16 + ll;
      float bias = bi1[col];
#pragma unroll
      for (int mt = 0; mt < 4; ++mt)
#pragma unroll
        for (int r = 0; r < 4; ++r)
          sH1[(mt * 16 + quad * 4 + r) * 264 + col] = f2bf(fmaxf(acc[mt][ni][r] + bias, 0.f));
    }
  }
  __syncthreads();

  // L2: relu(h1 @ Wi2 + bi2)  K=256, N=128
  {
    f32x4 acc[4][2] = {};
#pragma unroll 1
    for (int kt = 0; kt < 8; ++kt) {
      short8v b[2];
#pragma unroll
      for (int ni = 0; ni < 2; ++ni)
        b[ni] = *(const short8v*)&Wi2p[(((w * 2 + ni) * 8 + kt) * 64 + lane) * 8];
#pragma unroll
      for (int mt = 0; mt < 4; ++mt) {
        short8v a = *(const short8v*)&sH1[(mt * 16 + ll) * 264 + kt * 32 + quad * 8];
#pragma unroll
        for (int ni = 0; ni < 2; ++ni) acc[mt][ni] = mfma16(a, b[ni], acc[mt][ni]);
      }
    }
#pragma unroll
    for (int ni = 0; ni < 2; ++ni) {
      int col = (w * 2 + ni) * 16 + ll;
      float bias = bi2[col];
#pragma unroll
      for (int mt = 0; mt < 4; ++mt)
#pragma unroll
        for (int r = 0; r < 4; ++r)
          sH2[(mt * 16 + quad * 4 + r) * 136 + col] = f2bf(fmaxf(acc[mt][ni][r] + bias, 0.f));
    }
  }
  __syncthreads();

  // L3: x = h2 @ Wi3 + bi3 (NO relu)  K=128, N=128(pad, cols>=100 zero)
  {
    f32x4 acc[4][2] = {};
#pragma unroll 1
    for (int kt = 0; kt < 4; ++kt) {
      short8v b[2];
#pragma unroll
      for (int ni = 0; ni < 2; ++ni)
        b[ni] = *(const short8v*)&Wi3p[(((w * 2 + ni) * 4 + kt) * 64 + lane) * 8];
#pragma unroll
      for (int mt = 0; mt < 4; ++mt) {
        short8v a = *(const short8v*)&sH2[(mt * 16 + ll) * 136 + kt * 32 + quad * 8];
#pragma unroll
        for (int ni = 0; ni < 2; ++ni) acc[mt][ni] = mfma16(a, b[ni], acc[mt][ni]);
      }
    }
#pragma unroll
    for (int ni = 0; ni < 2; ++ni) {
      int col = (w * 2 + ni) * 16 + ll;
      float bias = (col < 100) ? bi3[col] : 0.f;
#pragma unroll
      for (int mt = 0; mt < 4; ++mt)
#pragma unroll
        for (int r = 0; r < 4; ++r) {
          float vv = (col < 100) ? (acc[mt][ni][r] + bias) : 0.f;
          sX[(mt * 16 + quad * 4 + r) * 136 + col] = f2bf(vv);
        }
    }
  }
  __syncthreads();

  // L4: u = x @ Wa ; v = x @ Wb   K=128, N=256 each (no bias/relu)
#pragma unroll 1
  for (int pass = 0; pass < 2; ++pass) {
    const short* Wp = pass ? Wbp : Wap;
    short* outg = pass ? v_g : u_g;
    f32x4 acc[4][4] = {};
#pragma unroll 1
    for (int kt = 0; kt < 4; ++kt) {
      short8v b[4];
#pragma unroll
      for (int ni = 0; ni < 4; ++ni)
        b[ni] = *(const short8v*)&Wp[(((w * 4 + ni) * 4 + kt) * 64 + lane) * 8];
#pragma unroll
      for (int mt = 0; mt < 4; ++mt) {
        short8v a = *(const short8v*)&sX[(mt * 16 + ll) * 136 + kt * 32 + quad * 8];
#pragma unroll
        for (int ni = 0; ni < 4; ++ni) acc[mt][ni] = mfma16(a, b[ni], acc[mt][ni]);
      }
    }
#pragma unroll
    for (int ni = 0; ni < 4; ++ni) {
      int col = (w * 4 + ni) * 16 + ll;
#pragma unroll
      for (int mt = 0; mt < 4; ++mt)
#pragma unroll
        for (int r = 0; r < 4; ++r)
          outg[(obj0 + mt * 16 + quad * 4 + r) * 256 + col] = f2bf(acc[mt][ni][r]);
    }
  }
}

// ---------- pair MLP: 4 batches/block, 144 rows, fused g2..g4 + sum-pool ----------
__launch_bounds__(256, 2)
__global__ void pair_kernel(const short* __restrict__ u_g, const short* __restrict__ v_g,
    const float* __restrict__ qb,
    const short* __restrict__ Wg2p, const short* __restrict__ Wg3p, const short* __restrict__ Wg4p,
    const float* __restrict__ bg2, const float* __restrict__ bg3, const float* __restrict__ bg4,
    float* __restrict__ g_g) {
  __shared__ __align__(16) short sH[144 * 264];  // 76,032 B
  __shared__ float pool[4 * 256];                 // 4 KB
  const int tid = threadIdx.x;
  const int lane = tid & 63, w = tid >> 6, quad = lane >> 4, ll = lane & 15;
  const int b0 = blockIdx.x * 4;

  for (int i = tid; i < 1024; i += 256) pool[i] = 0.f;

  // h1 = relu(u[j] + v[i] + qb), row = bb*36 + i*6 + j
#pragma unroll 1
  for (int it = 0; it < 36; ++it) {
    int vi = it * 256 + tid;
    int row = vi >> 6;
    int c4 = (vi & 63) * 4;
    int bb = row / 36;
    int p = row - bb * 36;
    int ii = p / 6, jj = p - ii * 6;
    short4v uu = *(const short4v*)&u_g[((b0 + bb) * 6 + jj) * 256 + c4];
    short4v vv = *(const short4v*)&v_g[((b0 + bb) * 6 + ii) * 256 + c4];
    f32x4 qq = *(const f32x4*)&qb[(b0 + bb) * 256 + c4];
    short4v o;
#pragma unroll
    for (int e = 0; e < 4; ++e)
      o[e] = f2bf(fmaxf(bf2f(uu[e]) + bf2f(vv[e]) + qq[e], 0.f));
    *(short4v*)&sH[row * 264 + c4] = o;
  }
  __syncthreads();

#pragma unroll 1
  for (int L = 0; L < 3; ++L) {
    const short* __restrict__ Wp = (L == 0) ? Wg2p : (L == 1) ? Wg3p : Wg4p;
    const float* __restrict__ bp = (L == 0) ? bg2 : (L == 1) ? bg3 : bg4;
    f32x4 acc[9][4] = {};
#pragma unroll 1
    for (int kt = 0; kt < 8; ++kt) {
      short8v b[4];
#pragma unroll
      for (int ni = 0; ni < 4; ++ni)
        b[ni] = *(const short8v*)&Wp[(((w * 4 + ni) * 8 + kt) * 64 + lane) * 8];
#pragma unroll
      for (int mt = 0; mt < 9; ++mt) {
        short8v a = *(const short8v*)&sH[(mt * 16 + ll) * 264 + kt * 32 + quad * 8];
#pragma unroll
        for (int ni = 0; ni < 4; ++ni) acc[mt][ni] = mfma16(a, b[ni], acc[mt][ni]);
      }
    }
    __syncthreads();  // all reads of sH complete before in-place overwrite
    if (L < 2) {
#pragma unroll
      for (int ni = 0; ni < 4; ++ni) {
        int col = (w * 4 + ni) * 16 + ll;
        float bias = bp[col];
#pragma unroll
        for (int mt = 0; mt < 9; ++mt)
#pragma unroll
          for (int r = 0; r < 4; ++r)
            sH[(mt * 16 + quad * 4 + r) * 264 + col] = f2bf(fmaxf(acc[mt][ni][r] + bias, 0.f));
      }
      __syncthreads();
    } else {
      // g4: relu then sum-pool. Each lane's 4 regs are 4 consecutive rows, and
      // 36 % 4 == 0 so a 4-row group never crosses a batch boundary.
#pragma unroll
      for (int ni = 0; ni < 4; ++ni) {
        int col = (w * 4 + ni) * 16 + ll;
        float bias = bp[col];
#pragma unroll
        for (int mt = 0; mt < 9; ++mt) {
          int bb = (mt * 16 + quad * 4) / 36;
          float s = 0.f;
#pragma unroll
          for (int r = 0; r < 4; ++r) s += fmaxf(acc[mt][ni][r] + bias, 0.f);
          atomicAdd(&pool[bb * 256 + col], s);
        }
      }
      __syncthreads();
      for (int t = tid; t < 1024; t += 256)
        g_g[(b0 + (t >> 8)) * 256 + (t & 255)] = pool[t];
    }
  }
}

// ---------- head helper: 64x256 @ 256x256 + bias + relu, LDS->LDS ----------
__device__ __forceinline__ void gemm64x256(const short* sInp, short* sOut,
    const short* __restrict__ Wp, const float* __restrict__ bias,
    int w, int lane, int quad, int ll) {
  f32x4 acc[4][4] = {};
#pragma unroll 1
  for (int kt = 0; kt < 8; ++kt) {
    short8v b[4];
#pragma unroll
    for (int ni = 0; ni < 4; ++ni)
      b[ni] = *(const short8v*)&Wp[(((w * 4 + ni) * 8 + kt) * 64 + lane) * 8];
#pragma unroll
    for (int mt = 0; mt < 4; ++mt) {
      short8v a = *(const short8v*)&sInp[(mt * 16 + ll) * 264 + kt * 32 + quad * 8];
#pragma unroll
      for (int ni = 0; ni < 4; ++ni) acc[mt][ni] = mfma16(a, b[ni], acc[mt][ni]);
    }
  }
#pragma unroll
  for (int ni = 0; ni < 4; ++ni) {
    int col = (w * 4 + ni) * 16 + ll;
    float bv = bias[col];
#pragma unroll
    for (int mt = 0; mt < 4; ++mt)
#pragma unroll
      for (int r = 0; r < 4; ++r)
        sOut[(mt * 16 + quad * 4 + r) * 264 + col] = f2bf(fmaxf(acc[mt][ni][r] + bv, 0.f));
  }
}

// ---------- head: g -> f -> o -> logits -> log_softmax ----------
__launch_bounds__(256, 2)
__global__ void head_kernel(const float* __restrict__ g_g,
    const short* __restrict__ Wfp, const float* __restrict__ bf_,
    const short* __restrict__ Wo1p, const float* __restrict__ bo1,
    const short* __restrict__ Wo2p, const float* __restrict__ bo2,
    float* __restrict__ outp) {
  __shared__ __align__(16) short sA[64 * 264];
  __shared__ __align__(16) short sB[64 * 264];
  __shared__ float sL[64 * 16];
  const int tid = threadIdx.x;
  const int lane = tid & 63, w = tid >> 6, quad = lane >> 4, ll = lane & 15;
  const int b0 = blockIdx.x * 64;

#pragma unroll 1
  for (int it = 0; it < 16; ++it) {
    int vi = it * 256 + tid;
    int row = vi >> 6, c4 = (vi & 63) * 4;
    f32x4 gv = *(const f32x4*)&g_g[(b0 + row) * 256 + c4];
    short4v o;
#pragma unroll
    for (int e = 0; e < 4; ++e) o[e] = f2bf(gv[e]);
    *(short4v*)&sA[row * 264 + c4] = o;
  }
  __syncthreads();
  gemm64x256(sA, sB, Wfp, bf_, w, lane, quad, ll);
  __syncthreads();
  gemm64x256(sB, sA, Wo1p, bo1, w, lane, quad, ll);
  __syncthreads();
  {
    f32x4 acc = {};
#pragma unroll 1
    for (int kt = 0; kt < 8; ++kt) {
      short8v b = *(const short8v*)&Wo2p[(kt * 64 + lane) * 8];
      short8v a = *(const short8v*)&sA[(w * 16 + ll) * 264 + kt * 32 + quad * 8];
      acc = mfma16(a, b, acc);
    }
#pragma unroll
    for (int r = 0; r < 4; ++r) {
      int row = w * 16 + quad * 4 + r;
      sL[row * 16 + ll] = acc[r] + ((ll < 10) ? bo2[ll] : 0.f);
    }
  }
  __syncthreads();
  if (tid < 64) {
    float m = -1e30f;
#pragma unroll
    for (int c = 0; c < 10; ++c) m = fmaxf(m, sL[tid * 16 + c]);
    float s = 0.f;
#pragma unroll
    for (int c = 0; c < 10; ++c) s += expf(sL[tid * 16 + c] - m);
    float ls = logf(s) + m;
#pragma unroll
    for (int c = 0; c < 10; ++c) outp[(b0 + tid) * 10 + c] = sL[tid * 16 + c] - ls;
  }
}

extern "C" void kernel_launch(void* const* d_in, const int* in_sizes, int n_in,
                              void* d_out, int out_size, void* d_ws, size_t ws_size,
                              hipStream_t stream) {
  const float* tabs = (const float*)d_in[0];
  const float* qst  = (const float*)d_in[1];
  const float* Wi1 = (const float*)d_in[2];  const float* bi1 = (const float*)d_in[3];
  const float* Wi2 = (const float*)d_in[4];  const float* bi2 = (const float*)d_in[5];
  const float* Wi3 = (const float*)d_in[6];  const float* bi3 = (const float*)d_in[7];
  const float* Wg1 = (const float*)d_in[8];  const float* bg1 = (const float*)d_in[9];
  const float* Wg2 = (const float*)d_in[10]; const float* bg2 = (const float*)d_in[11];
  const float* Wg3 = (const float*)d_in[12]; const float* bg3 = (const float*)d_in[13];
  const float* Wg4 = (const float*)d_in[14]; const float* bg4 = (const float*)d_in[15];
  const float* Wf  = (const float*)d_in[16]; const float* bf_ = (const float*)d_in[17];
  const float* Wo1 = (const float*)d_in[18]; const float* bo1 = (const float*)d_in[19];
  const float* Wo2 = (const float*)d_in[20]; const float* bo2 = (const float*)d_in[21];
  float* outp = (float*)d_out;
  (void)in_sizes; (void)n_in; (void)out_size; (void)ws_size;

  char* ws = (char*)d_ws;
  size_t off = 0;
  auto alloc = [&](size_t bytes) { void* p = ws + off; off += (bytes + 255) & ~(size_t)255; return p; };
  const size_t BN = 16384ull * 6;
  short* u_g = (short*)alloc(BN * 256 * 2);          // 50.3 MB
  short* v_g = (short*)alloc(BN * 256 * 2);          // 50.3 MB
  float* qb  = (float*)alloc(16384ull * 256 * 4);    // 16.8 MB
  float* g_g = (float*)alloc(16384ull * 256 * 4);    // 16.8 MB
  short* Wi1p = (short*)alloc(16 * 1 * 64 * 8 * 2);
  short* Wi2p = (short*)alloc(8 * 8 * 64 * 8 * 2);
  short* Wi3p = (short*)alloc(8 * 4 * 64 * 8 * 2);
  short* Wap  = (short*)alloc(16 * 4 * 64 * 8 * 2);
  short* Wbp  = (short*)alloc(16 * 4 * 64 * 8 * 2);
  short* Wg2p = (short*)alloc(16 * 8 * 64 * 8 * 2);
  short* Wg3p = (short*)alloc(16 * 8 * 64 * 8 * 2);
  short* Wg4p = (short*)alloc(16 * 8 * 64 * 8 * 2);
  short* Wfp  = (short*)alloc(16 * 8 * 64 * 8 * 2);
  short* Wo1p = (short*)alloc(16 * 8 * 64 * 8 * 2);
  short* Wo2p = (short*)alloc(1 * 8 * 64 * 8 * 2);

  auto pp = [&](const float* src, short* dst, int Ks, int Ns, int KT, int NT) {
    int total = NT * KT * 64;
    prepack_b<<<(total + 255) / 256, 256, 0, stream>>>(src, dst, Ks, Ns, KT, NT);
  };
  pp(Wi1, Wi1p, 10, 256, 1, 16);
  pp(Wi2, Wi2p, 256, 128, 8, 8);
  pp(Wi3, Wi3p, 128, 100, 4, 8);
  pp(Wg1,             Wap, 100, 256, 4, 16);   // rows 0..99   (x_j side -> u)
  pp(Wg1 + 100 * 256, Wbp, 100, 256, 4, 16);   // rows 100..199 (x_i side -> v)
  pp(Wg2, Wg2p, 256, 256, 8, 16);
  pp(Wg3, Wg3p, 256, 256, 8, 16);
  pp(Wg4, Wg4p, 256, 256, 8, 16);
  pp(Wf,  Wfp,  256, 256, 8, 16);
  pp(Wo1, Wo1p, 256, 256, 8, 16);
  pp(Wo2, Wo2p, 256, 10, 8, 1);

  qb_kernel<<<16384, 256, 0, stream>>>(qst, Wg1, bg1, qb);
  enc_kernel<<<1536, 256, 0, stream>>>(tabs, bi1, bi2, bi3, Wi1p, Wi2p, Wi3p, Wap, Wbp, u_g, v_g);
  pair_kernel<<<4096, 256, 0, stream>>>(u_g, v_g, qb, Wg2p, Wg3p, Wg4p, bg2, bg3, bg4, g_g);
  head_kernel<<<256, 256, 0, stream>>>(g_g, Wfp, bf_, Wo1p, bo1, Wo2p, bo2, outp);
}

// Round 2
// 613.667 us; speedup vs baseline: 1.1060x; 1.1060x over previous
//
#include <hip/hip_runtime.h>
#include <hip/hip_bf16.h>
#include <stdint.h>

// ---------- types ----------
typedef __attribute__((ext_vector_type(8))) __bf16 bf16x8;
typedef __attribute__((ext_vector_type(8))) short short8v;
typedef __attribute__((ext_vector_type(4))) short short4v;
typedef __attribute__((ext_vector_type(4))) float f32x4;

__device__ __forceinline__ float bf2f(short u) {
  return __builtin_bit_cast(float, (uint32_t)((uint32_t)(uint16_t)u << 16));
}
__device__ __forceinline__ short f2bf(float f) {
  uint32_t x = __builtin_bit_cast(uint32_t, f);
  x += 0x7FFFu + ((x >> 16) & 1u);
  return (short)(x >> 16);
}
__device__ __forceinline__ f32x4 mfma16(short8v a, short8v b, f32x4 c) {
  return __builtin_amdgcn_mfma_f32_16x16x32_bf16(
      __builtin_bit_cast(bf16x8, a), __builtin_bit_cast(bf16x8, b), c, 0, 0, 0);
}

// ---------- merged prepack: all 11 weights in ONE launch ----------
// dst layout per weight: [nt][kt][lane][8 bf16]; B[k=kt*32+(lane>>4)*8+j][n=nt*16+(lane&15)]
struct PPDesc { const float* src; short* dst; int Ks, Ns, KT, NT, tile_base; };
struct PPArgs { PPDesc d[11]; int n_desc; int total_tiles; };

__global__ void prepack_all(PPArgs args) {
  int idx = blockIdx.x * 256 + threadIdx.x;
  int tile = idx >> 6;
  if (tile >= args.total_tiles) return;
  int lane = idx & 63;
  int e = 0;
  while (e + 1 < args.n_desc && args.d[e + 1].tile_base <= tile) ++e;
  const PPDesc D = args.d[e];
  int t = tile - D.tile_base;
  int kt = t % D.KT, nt = t / D.KT;
  int n = nt * 16 + (lane & 15);
  int kbase = kt * 32 + ((lane >> 4) * 8);
  short8v o;
#pragma unroll
  for (int j = 0; j < 8; ++j) {
    int k = kbase + j;
    o[j] = f2bf((k < D.Ks && n < D.Ns) ? D.src[k * D.Ns + n] : 0.f);
  }
  *(short8v*)&D.dst[((size_t)t * 64 + lane) * 8] = o;
}

// ---------- qb[b,c] = qst[b] @ Wg1[200:211] + bg1 (32 batches/block) ----------
__global__ void qb_kernel(const float* __restrict__ qst, const float* __restrict__ Wg1,
                          const float* __restrict__ bg1, float* __restrict__ qb) {
  int c = threadIdx.x;
  int b0 = blockIdx.x * 32;
  float wcol[11];
#pragma unroll
  for (int k = 0; k < 11; ++k) wcol[k] = Wg1[(200 + k) * 256 + c];
  float bias = bg1[c];
#pragma unroll 1
  for (int bb = 0; bb < 32; ++bb) {
    int b = b0 + bb;
    float acc = bias;
#pragma unroll
    for (int k = 0; k < 11; ++k) acc += qst[b * 11 + k] * wcol[k];
    qb[b * 256 + c] = acc;
  }
}

// ---------- encoder: tabs[64 rows x 10] -> x -> u,v (bf16, [obj][256]) ----------
__launch_bounds__(256, 2)
__global__ void enc_kernel(const float* __restrict__ tabs,
    const float* __restrict__ bi1, const float* __restrict__ bi2, const float* __restrict__ bi3,
    const short* __restrict__ Wi1p, const short* __restrict__ Wi2p, const short* __restrict__ Wi3p,
    const short* __restrict__ Wap, const short* __restrict__ Wbp,
    short* __restrict__ u_g, short* __restrict__ v_g) {
  __shared__ __align__(16) short sIn[64 * 40];
  __shared__ __align__(16) short sH1[64 * 264];
  __shared__ __align__(16) short sH2[64 * 136];
  __shared__ __align__(16) short sX [64 * 136];
  const int tid = threadIdx.x;
  const int lane = tid & 63, w = tid >> 6, quad = lane >> 4, ll = lane & 15;
  const int obj0 = blockIdx.x * 64;

  for (int idx = tid; idx < 64 * 40; idx += 256) {
    int r = idx / 40, k = idx - r * 40;
    float v = (k < 10) ? tabs[(obj0 + r) * 10 + k] : 0.f;
    sIn[idx] = f2bf(v);
  }
  __syncthreads();

  // L1: relu(in @ Wi1 + bi1)  K=32(pad), N=256
  {
    f32x4 acc[4][4] = {};
    short8v a[4];
#pragma unroll
    for (int mt = 0; mt < 4; ++mt)
      a[mt] = *(const short8v*)&sIn[(mt * 16 + ll) * 40 + quad * 8];
#pragma unroll
    for (int ni = 0; ni < 4; ++ni) {
      short8v b = *(const short8v*)&Wi1p[((w * 4 + ni) * 64 + lane) * 8];
#pragma unroll
      for (int mt = 0; mt < 4; ++mt) acc[mt][ni] = mfma16(a[mt], b, acc[mt][ni]);
    }
#pragma unroll
    for (int ni = 0; ni < 4; ++ni) {
      int col = (w * 4 + ni) * 16 + ll;
      float bias = bi1[col];
#pragma unroll
      for (int mt = 0; mt < 4; ++mt)
#pragma unroll
        for (int r = 0; r < 4; ++r)
          sH1[(mt * 16 + quad * 4 + r) * 264 + col] = f2bf(fmaxf(acc[mt][ni][r] + bias, 0.f));
    }
  }
  __syncthreads();

  // L2: relu(h1 @ Wi2 + bi2)  K=256, N=128
  {
    f32x4 acc[4][2] = {};
#pragma unroll 1
    for (int kt = 0; kt < 8; ++kt) {
      short8v b[2];
#pragma unroll
      for (int ni = 0; ni < 2; ++ni)
        b[ni] = *(const short8v*)&Wi2p[(((w * 2 + ni) * 8 + kt) * 64 + lane) * 8];
#pragma unroll
      for (int mt = 0; mt < 4; ++mt) {
        short8v a = *(const short8v*)&sH1[(mt * 16 + ll) * 264 + kt * 32 + quad * 8];
#pragma unroll
        for (int ni = 0; ni < 2; ++ni) acc[mt][ni] = mfma16(a, b[ni], acc[mt][ni]);
      }
    }
#pragma unroll
    for (int ni = 0; ni < 2; ++ni) {
      int col = (w * 2 + ni) * 16 + ll;
      float bias = bi2[col];
#pragma unroll
      for (int mt = 0; mt < 4; ++mt)
#pragma unroll
        for (int r = 0; r < 4; ++r)
          sH2[(mt * 16 + quad * 4 + r) * 136 + col] = f2bf(fmaxf(acc[mt][ni][r] + bias, 0.f));
    }
  }
  __syncthreads();

  // L3: x = h2 @ Wi3 + bi3 (NO relu)  K=128, N=128(pad, cols>=100 zero)
  {
    f32x4 acc[4][2] = {};
#pragma unroll 1
    for (int kt = 0; kt < 4; ++kt) {
      short8v b[2];
#pragma unroll
      for (int ni = 0; ni < 2; ++ni)
        b[ni] = *(const short8v*)&Wi3p[(((w * 2 + ni) * 4 + kt) * 64 + lane) * 8];
#pragma unroll
      for (int mt = 0; mt < 4; ++mt) {
        short8v a = *(const short8v*)&sH2[(mt * 16 + ll) * 136 + kt * 32 + quad * 8];
#pragma unroll
        for (int ni = 0; ni < 2; ++ni) acc[mt][ni] = mfma16(a, b[ni], acc[mt][ni]);
      }
    }
#pragma unroll
    for (int ni = 0; ni < 2; ++ni) {
      int col = (w * 2 + ni) * 16 + ll;
      float bias = (col < 100) ? bi3[col] : 0.f;
#pragma unroll
      for (int mt = 0; mt < 4; ++mt)
#pragma unroll
        for (int r = 0; r < 4; ++r) {
          float vv = (col < 100) ? (acc[mt][ni][r] + bias) : 0.f;
          sX[(mt * 16 + quad * 4 + r) * 136 + col] = f2bf(vv);
        }
    }
  }
  __syncthreads();

  // L4: u = x @ Wa ; v = x @ Wb   K=128, N=256 each
#pragma unroll 1
  for (int pass = 0; pass < 2; ++pass) {
    const short* Wp = pass ? Wbp : Wap;
    short* outg = pass ? v_g : u_g;
    f32x4 acc[4][4] = {};
#pragma unroll 1
    for (int kt = 0; kt < 4; ++kt) {
      short8v b[4];
#pragma unroll
      for (int ni = 0; ni < 4; ++ni)
        b[ni] = *(const short8v*)&Wp[(((w * 4 + ni) * 4 + kt) * 64 + lane) * 8];
#pragma unroll
      for (int mt = 0; mt < 4; ++mt) {
        short8v a = *(const short8v*)&sX[(mt * 16 + ll) * 136 + kt * 32 + quad * 8];
#pragma unroll
        for (int ni = 0; ni < 4; ++ni) acc[mt][ni] = mfma16(a, b[ni], acc[mt][ni]);
      }
    }
#pragma unroll
    for (int ni = 0; ni < 4; ++ni) {
      int col = (w * 4 + ni) * 16 + ll;
#pragma unroll
      for (int mt = 0; mt < 4; ++mt)
#pragma unroll
        for (int r = 0; r < 4; ++r)
          outg[(obj0 + mt * 16 + quad * 4 + r) * 256 + col] = f2bf(acc[mt][ni][r]);
    }
  }
}

// ---------- pair MLP: 2 batches/block, 72 rows (pad->80), fused g2..g4 + pool ----------
// LDS 44.3 KB -> 3 blocks/CU (12 waves). Weight loads software-pipelined (ping-pong).
__launch_bounds__(256, 3)
__global__ void pair_kernel(const short* __restrict__ u_g, const short* __restrict__ v_g,
    const float* __restrict__ qb,
    const short* __restrict__ Wg2p, const short* __restrict__ Wg3p, const short* __restrict__ Wg4p,
    const float* __restrict__ bg2, const float* __restrict__ bg3, const float* __restrict__ bg4,
    float* __restrict__ g_g) {
  __shared__ __align__(16) short sH[80 * 264];   // 42,240 B (rows 72..79 pad)
  __shared__ float pool[2 * 256];                // 2 KB
  const int tid = threadIdx.x;
  const int lane = tid & 63, w = tid >> 6, quad = lane >> 4, ll = lane & 15;
  const int b0 = blockIdx.x * 2;

  for (int i = tid; i < 512; i += 256) pool[i] = 0.f;
  // zero pad rows once (keeps MFMA inputs non-NaN; pad rows never pooled)
  for (int i = tid; i < 528; i += 256)
    *(short4v*)&sH[72 * 264 + i * 4] = short4v{0, 0, 0, 0};

  // h1 = relu(u[j] + v[i] + qb), row = bb*36 + i*6 + j  (72 real rows, pipelined)
  {
    short4v u_c, v_c; f32x4 q_c; int sh_c;
    {
      int vi = tid;                       // it = 0
      int row = vi >> 6, c4 = (vi & 63) * 4;
      int bb = row / 36, p = row - bb * 36;
      int i2 = p / 6, j2 = p - i2 * 6;
      u_c = *(const short4v*)&u_g[((b0 + bb) * 6 + j2) * 256 + c4];
      v_c = *(const short4v*)&v_g[((b0 + bb) * 6 + i2) * 256 + c4];
      q_c = *(const f32x4*)&qb[(b0 + bb) * 256 + c4];
      sh_c = row * 264 + c4;
    }
#pragma unroll 1
    for (int it = 0; it < 18; ++it) {
      short4v u_n = {}, v_n = {}; f32x4 q_n = {}; int sh_n = 0;
      if (it < 17) {
        int vi = (it + 1) * 256 + tid;
        int row = vi >> 6, c4 = (vi & 63) * 4;
        int bb = row / 36, p = row - bb * 36;
        int i2 = p / 6, j2 = p - i2 * 6;
        u_n = *(const short4v*)&u_g[((b0 + bb) * 6 + j2) * 256 + c4];
        v_n = *(const short4v*)&v_g[((b0 + bb) * 6 + i2) * 256 + c4];
        q_n = *(const f32x4*)&qb[(b0 + bb) * 256 + c4];
        sh_n = row * 264 + c4;
      }
      short4v o;
#pragma unroll
      for (int e = 0; e < 4; ++e)
        o[e] = f2bf(fmaxf(bf2f(u_c[e]) + bf2f(v_c[e]) + q_c[e], 0.f));
      *(short4v*)&sH[sh_c] = o;
      u_c = u_n; v_c = v_n; q_c = q_n; sh_c = sh_n;
    }
  }
  __syncthreads();

#pragma unroll 1
  for (int L = 0; L < 3; ++L) {
    const short* __restrict__ Wp = (L == 0) ? Wg2p : (L == 1) ? Wg3p : Wg4p;
    const float* __restrict__ bp = (L == 0) ? bg2 : (L == 1) ? bg3 : bg4;
    f32x4 acc[5][4] = {};
    short8v bA[4], bB[4];
#pragma unroll
    for (int ni = 0; ni < 4; ++ni)
      bA[ni] = *(const short8v*)&Wp[(((w * 4 + ni) * 8 + 0) * 64 + lane) * 8];
#pragma unroll 1
    for (int kt = 0; kt < 8; kt += 2) {
      // prefetch kt+1 weights while computing kt
#pragma unroll
      for (int ni = 0; ni < 4; ++ni)
        bB[ni] = *(const short8v*)&Wp[(((w * 4 + ni) * 8 + kt + 1) * 64 + lane) * 8];
      {
        short8v a[5];
#pragma unroll
        for (int mt = 0; mt < 5; ++mt)
          a[mt] = *(const short8v*)&sH[(mt * 16 + ll) * 264 + kt * 32 + quad * 8];
#pragma unroll
        for (int mt = 0; mt < 5; ++mt)
#pragma unroll
          for (int ni = 0; ni < 4; ++ni) acc[mt][ni] = mfma16(a[mt], bA[ni], acc[mt][ni]);
      }
      if (kt + 2 < 8) {
#pragma unroll
        for (int ni = 0; ni < 4; ++ni)
          bA[ni] = *(const short8v*)&Wp[(((w * 4 + ni) * 8 + kt + 2) * 64 + lane) * 8];
      }
      {
        short8v a[5];
#pragma unroll
        for (int mt = 0; mt < 5; ++mt)
          a[mt] = *(const short8v*)&sH[(mt * 16 + ll) * 264 + (kt + 1) * 32 + quad * 8];
#pragma unroll
        for (int mt = 0; mt < 5; ++mt)
#pragma unroll
          for (int ni = 0; ni < 4; ++ni) acc[mt][ni] = mfma16(a[mt], bB[ni], acc[mt][ni]);
      }
    }
    __syncthreads();  // all reads of sH done before in-place overwrite
    if (L < 2) {
#pragma unroll
      for (int ni = 0; ni < 4; ++ni) {
        int col = (w * 4 + ni) * 16 + ll;
        float bias = bp[col];
#pragma unroll
        for (int mt = 0; mt < 5; ++mt)
#pragma unroll
          for (int r = 0; r < 4; ++r)
            sH[(mt * 16 + quad * 4 + r) * 264 + col] = f2bf(fmaxf(acc[mt][ni][r] + bias, 0.f));
      }
      __syncthreads();
    } else {
      // g4: relu + sum-pool. 4-row groups never cross the row-36 batch boundary.
#pragma unroll
      for (int ni = 0; ni < 4; ++ni) {
        int col = (w * 4 + ni) * 16 + ll;
        float bias = bp[col];
#pragma unroll
        for (int mt = 0; mt < 5; ++mt) {
          int rbase = mt * 16 + quad * 4;
          if (rbase < 72) {
            int bb = rbase / 36;
            float s = 0.f;
#pragma unroll
            for (int r = 0; r < 4; ++r) s += fmaxf(acc[mt][ni][r] + bias, 0.f);
            atomicAdd(&pool[bb * 256 + col], s);
          }
        }
      }
      __syncthreads();
      for (int t = tid; t < 512; t += 256)
        g_g[(b0 + (t >> 8)) * 256 + (t & 255)] = pool[t];
    }
  }
}

// ---------- head helper: 64x256 @ 256x256 + bias + relu, LDS->LDS ----------
__device__ __forceinline__ void gemm64x256(const short* sInp, short* sOut,
    const short* __restrict__ Wp, const float* __restrict__ bias,
    int w, int lane, int quad, int ll) {
  f32x4 acc[4][4] = {};
#pragma unroll 1
  for (int kt = 0; kt < 8; ++kt) {
    short8v b[4];
#pragma unroll
    for (int ni = 0; ni < 4; ++ni)
      b[ni] = *(const short8v*)&Wp[(((w * 4 + ni) * 8 + kt) * 64 + lane) * 8];
#pragma unroll
    for (int mt = 0; mt < 4; ++mt) {
      short8v a = *(const short8v*)&sInp[(mt * 16 + ll) * 264 + kt * 32 + quad * 8];
#pragma unroll
      for (int ni = 0; ni < 4; ++ni) acc[mt][ni] = mfma16(a, b[ni], acc[mt][ni]);
    }
  }
#pragma unroll
  for (int ni = 0; ni < 4; ++ni) {
    int col = (w * 4 + ni) * 16 + ll;
    float bv = bias[col];
#pragma unroll
    for (int mt = 0; mt < 4; ++mt)
#pragma unroll
      for (int r = 0; r < 4; ++r)
        sOut[(mt * 16 + quad * 4 + r) * 264 + col] = f2bf(fmaxf(acc[mt][ni][r] + bv, 0.f));
  }
}

// ---------- head: g -> f -> o -> logits -> log_softmax ----------
__launch_bounds__(256, 2)
__global__ void head_kernel(const float* __restrict__ g_g,
    const short* __restrict__ Wfp, const float* __restrict__ bf_,
    const short* __restrict__ Wo1p, const float* __restrict__ bo1,
    const short* __restrict__ Wo2p, const float* __restrict__ bo2,
    float* __restrict__ outp) {
  __shared__ __align__(16) short sA[64 * 264];
  __shared__ __align__(16) short sB[64 * 264];
  __shared__ float sL[64 * 16];
  const int tid = threadIdx.x;
  const int lane = tid & 63, w = tid >> 6, quad = lane >> 4, ll = lane & 15;
  const int b0 = blockIdx.x * 64;

#pragma unroll 1
  for (int it = 0; it < 16; ++it) {
    int vi = it * 256 + tid;
    int row = vi >> 6, c4 = (vi & 63) * 4;
    f32x4 gv = *(const f32x4*)&g_g[(b0 + row) * 256 + c4];
    short4v o;
#pragma unroll
    for (int e = 0; e < 4; ++e) o[e] = f2bf(gv[e]);
    *(short4v*)&sA[row * 264 + c4] = o;
  }
  __syncthreads();
  gemm64x256(sA, sB, Wfp, bf_, w, lane, quad, ll);
  __syncthreads();
  gemm64x256(sB, sA, Wo1p, bo1, w, lane, quad, ll);
  __syncthreads();
  {
    f32x4 acc = {};
#pragma unroll 1
    for (int kt = 0; kt < 8; ++kt) {
      short8v b = *(const short8v*)&Wo2p[(kt * 64 + lane) * 8];
      short8v a = *(const short8v*)&sA[(w * 16 + ll) * 264 + kt * 32 + quad * 8];
      acc = mfma16(a, b, acc);
    }
#pragma unroll
    for (int r = 0; r < 4; ++r) {
      int row = w * 16 + quad * 4 + r;
      sL[row * 16 + ll] = acc[r] + ((ll < 10) ? bo2[ll] : 0.f);
    }
  }
  __syncthreads();
  if (tid < 64) {
    float m = -1e30f;
#pragma unroll
    for (int c = 0; c < 10; ++c) m = fmaxf(m, sL[tid * 16 + c]);
    float s = 0.f;
#pragma unroll
    for (int c = 0; c < 10; ++c) s += expf(sL[tid * 16 + c] - m);
    float ls = logf(s) + m;
#pragma unroll
    for (int c = 0; c < 10; ++c) outp[(b0 + tid) * 10 + c] = sL[tid * 16 + c] - ls;
  }
}

extern "C" void kernel_launch(void* const* d_in, const int* in_sizes, int n_in,
                              void* d_out, int out_size, void* d_ws, size_t ws_size,
                              hipStream_t stream) {
  const float* tabs = (const float*)d_in[0];
  const float* qst  = (const float*)d_in[1];
  const float* Wi1 = (const float*)d_in[2];  const float* bi1 = (const float*)d_in[3];
  const float* Wi2 = (const float*)d_in[4];  const float* bi2 = (const float*)d_in[5];
  const float* Wi3 = (const float*)d_in[6];  const float* bi3 = (const float*)d_in[7];
  const float* Wg1 = (const float*)d_in[8];  const float* bg1 = (const float*)d_in[9];
  const float* Wg2 = (const float*)d_in[10]; const float* bg2 = (const float*)d_in[11];
  const float* Wg3 = (const float*)d_in[12]; const float* bg3 = (const float*)d_in[13];
  const float* Wg4 = (const float*)d_in[14]; const float* bg4 = (const float*)d_in[15];
  const float* Wf  = (const float*)d_in[16]; const float* bf_ = (const float*)d_in[17];
  const float* Wo1 = (const float*)d_in[18]; const float* bo1 = (const float*)d_in[19];
  const float* Wo2 = (const float*)d_in[20]; const float* bo2 = (const float*)d_in[21];
  float* outp = (float*)d_out;
  (void)in_sizes; (void)n_in; (void)out_size; (void)ws_size;

  char* ws = (char*)d_ws;
  size_t off = 0;
  auto alloc = [&](size_t bytes) { void* p = ws + off; off += (bytes + 255) & ~(size_t)255; return p; };
  const size_t BN = 16384ull * 6;
  short* u_g = (short*)alloc(BN * 256 * 2);
  short* v_g = (short*)alloc(BN * 256 * 2);
  float* qb  = (float*)alloc(16384ull * 256 * 4);
  float* g_g = (float*)alloc(16384ull * 256 * 4);
  short* Wi1p = (short*)alloc(16 * 1 * 64 * 8 * 2);
  short* Wi2p = (short*)alloc(8 * 8 * 64 * 8 * 2);
  short* Wi3p = (short*)alloc(8 * 4 * 64 * 8 * 2);
  short* Wap  = (short*)alloc(16 * 4 * 64 * 8 * 2);
  short* Wbp  = (short*)alloc(16 * 4 * 64 * 8 * 2);
  short* Wg2p = (short*)alloc(16 * 8 * 64 * 8 * 2);
  short* Wg3p = (short*)alloc(16 * 8 * 64 * 8 * 2);
  short* Wg4p = (short*)alloc(16 * 8 * 64 * 8 * 2);
  short* Wfp  = (short*)alloc(16 * 8 * 64 * 8 * 2);
  short* Wo1p = (short*)alloc(16 * 8 * 64 * 8 * 2);
  short* Wo2p = (short*)alloc(1 * 8 * 64 * 8 * 2);

  PPArgs pa;
  int tb = 0, nd = 0;
  auto add = [&](const float* src, short* dst, int Ks, int Ns, int KT, int NT) {
    pa.d[nd++] = PPDesc{src, dst, Ks, Ns, KT, NT, tb};
    tb += KT * NT;
  };
  add(Wi1, Wi1p, 10, 256, 1, 16);
  add(Wi2, Wi2p, 256, 128, 8, 8);
  add(Wi3, Wi3p, 128, 100, 4, 8);
  add(Wg1,             Wap, 100, 256, 4, 16);
  add(Wg1 + 100 * 256, Wbp, 100, 256, 4, 16);
  add(Wg2, Wg2p, 256, 256, 8, 16);
  add(Wg3, Wg3p, 256, 256, 8, 16);
  add(Wg4, Wg4p, 256, 256, 8, 16);
  add(Wf,  Wfp,  256, 256, 8, 16);
  add(Wo1, Wo1p, 256, 256, 8, 16);
  add(Wo2, Wo2p, 256, 10, 8, 1);
  pa.n_desc = nd;
  pa.total_tiles = tb;
  prepack_all<<<(tb * 64 + 255) / 256, 256, 0, stream>>>(pa);

  qb_kernel<<<512, 256, 0, stream>>>(qst, Wg1, bg1, qb);
  enc_kernel<<<1536, 256, 0, stream>>>(tabs, bi1, bi2, bi3, Wi1p, Wi2p, Wi3p, Wap, Wbp, u_g, v_g);
  pair_kernel<<<8192, 256, 0, stream>>>(u_g, v_g, qb, Wg2p, Wg3p, Wg4p, bg2, bg3, bg4, g_g);
  head_kernel<<<256, 256, 0, stream>>>(g_g, Wfp, bf_, Wo1p, bo1, Wo2p, bo2, outp);
}